// Round 1
// baseline (216.133 us; speedup 1.0000x reference)
//
#include <hip/hip_runtime.h>

// ReflectionFusion: out = p*x + (1-p)*boxmean9x9(sum_c x)  (zero padding)
// x: (32,3,512,512) f32, p: (32,1,512,512) f32, out: (32,3,512,512) f32.
// All 3 output channels of the conv are identical (filter is all-ones over
// input channels), so compute channel-sum once, separable 9x9 box in LDS.

#define TX 64
#define TY 64
#define HALO 4
#define THW (TY + 2 * HALO)  // 72
#define TWW (TX + 2 * HALO)  // 72

__global__ __launch_bounds__(256) void reflection_fusion_kernel(
    const float* __restrict__ x, const float* __restrict__ p,
    float* __restrict__ out, int B, int H, int W) {
  __shared__ float csum[THW][TWW];  // 72x72 channel-sum with halo (20.7 KB)
  __shared__ float hsum[THW][TX];   // 72x64 horizontal 9-sum (18.4 KB)

  const int tid = threadIdx.x;
  const int b = blockIdx.z;
  const int x0 = blockIdx.x * TX;
  const int y0 = blockIdx.y * TY;
  const long HW = (long)H * W;
  const float* xb = x + (long)b * 3 * HW;

  // Stage 1: halo load + channel sum into LDS
  for (int i = tid; i < THW * TWW; i += 256) {
    int r = i / TWW;
    int cc = i - r * TWW;
    int gy = y0 + r - HALO;
    int gx = x0 + cc - HALO;
    float s = 0.f;
    if (gy >= 0 && gy < H && gx >= 0 && gx < W) {
      long base = (long)gy * W + gx;
      s = xb[base] + xb[base + HW] + xb[base + 2 * HW];
    }
    csum[r][cc] = s;
  }
  __syncthreads();

  // Stage 2: horizontal 9-tap box sum (72 rows x 64 cols)
  for (int i = tid; i < THW * TX; i += 256) {
    int r = i >> 6;          // /64
    int cc = i & (TX - 1);   // %64
    float s = 0.f;
#pragma unroll
    for (int k = 0; k < 9; ++k) s += csum[r][cc + k];
    hsum[r][cc] = s;
  }
  __syncthreads();

  // Stage 3: vertical 9-tap sum + fuse + store (64x64 outputs, 16 per thread)
  const float inv81 = 1.0f / 81.0f;
  const int cc = tid & 63;
  const int r0 = tid >> 6;  // 0..3
#pragma unroll
  for (int it = 0; it < 16; ++it) {
    int rr = r0 + it * 4;
    float s = 0.f;
#pragma unroll
    for (int k = 0; k < 9; ++k) s += hsum[rr + k][cc];
    float m = s * inv81;
    int gy = y0 + rr;
    int gx = x0 + cc;
    long pix = (long)gy * W + gx;
    float pv = p[(long)b * HW + pix];
    float om = 1.0f - pv;
#pragma unroll
    for (int c = 0; c < 3; ++c) {
      float xv = xb[(long)c * HW + pix];
      out[((long)b * 3 + c) * HW + pix] = pv * xv + om * m;
    }
  }
}

extern "C" void kernel_launch(void* const* d_in, const int* in_sizes, int n_in,
                              void* d_out, int out_size, void* d_ws, size_t ws_size,
                              hipStream_t stream) {
  const float* x = (const float*)d_in[0];
  const float* p = (const float*)d_in[1];
  float* out = (float*)d_out;

  const int H = 512, W = 512;
  const int B = in_sizes[1] / (H * W);  // p is (B,1,H,W) -> 32

  dim3 grid(W / TX, H / TY, B);  // (8, 8, 32)
  dim3 block(256);
  reflection_fusion_kernel<<<grid, block, 0, stream>>>(x, p, out, B, H, W);
}

// Round 4
// 215.599 us; speedup vs baseline: 1.0025x; 1.0025x over previous
//
#include <hip/hip_runtime.h>

// ReflectionFusion: out = p*x + (1-p)*boxmean9x9(sum_c x)  (zero padding)
// x: (32,3,512,512) f32, p: (32,1,512,512) f32, out: (32,3,512,512) f32.
// All 3 conv output channels are identical (all-ones filter over in-channels):
// channel-sum once -> separable 9x9 box -> fuse.
//
// R1 design: single LDS buffer (csum 72x72 f32, 20.7 KB -> 7 blocks/CU vs 4),
// one barrier. Stage 1 uses float4 loads (halo=4=vec width so every float4 is
// fully in- or out-of-bounds, 16B-aligned). Stage 2: each thread owns one
// column x 16-row strip; 24 horizontal 9-sums into registers (stride-4B LDS
// reads = 2 lanes/bank = conflict-free), running vertical window, fully
// unrolled fuse with ~64 independent global loads in flight per thread.

#define TX 64
#define TY 64
#define HALO 4
#define THW (TY + 2 * HALO)  // 72
#define TWW (TX + 2 * HALO)  // 72

__global__ __launch_bounds__(256) void reflection_fusion_kernel(
    const float* __restrict__ x, const float* __restrict__ p,
    float* __restrict__ out, int H, int W) {
  __shared__ __align__(16) float csum[THW][TWW];  // 20.7 KB

  const int tid = threadIdx.x;
  const int b = blockIdx.z;
  const int x0 = blockIdx.x * TX;
  const int y0 = blockIdx.y * TY;
  const long HW = (long)H * W;
  const float* xb = x + (long)b * 3 * HW;
  const float* pb = p + (long)b * HW;
  float* ob = out + (long)b * 3 * HW;

  // ---- Stage 1: halo load (float4) + channel sum into LDS ----
  // 72 rows x 18 float4-chunks = 1296 chunks; 256 threads -> 6 passes.
  const int NCHUNK = THW * (TWW / 4);  // 1296
#pragma unroll
  for (int pass = 0; pass < 6; ++pass) {
    int i = tid + pass * 256;
    if (i < NCHUNK) {
      int r = (unsigned)i / 18u;
      int j = i - r * 18;
      int gy = y0 + r - HALO;
      int gx = x0 + 4 * j - HALO;  // multiple of 4 -> 16B aligned when in range
      float4 s = make_float4(0.f, 0.f, 0.f, 0.f);
      if ((unsigned)gy < (unsigned)H && gx >= 0 && gx + 4 <= W) {
        const float* base = xb + (long)gy * W + gx;
        float4 a = *(const float4*)(base);
        float4 c1 = *(const float4*)(base + HW);
        float4 c2 = *(const float4*)(base + 2 * HW);
        s.x = a.x + c1.x + c2.x;
        s.y = a.y + c1.y + c2.y;
        s.z = a.z + c1.z + c2.z;
        s.w = a.w + c1.w + c2.w;
      }
      *(float4*)&csum[r][4 * j] = s;
    }
  }
  __syncthreads();

  // ---- Stage 2: per-thread column strip, registers only ----
  const int cc = tid & 63;        // output column within tile
  const int rg = tid >> 6;        // 0..3 -> 16-row strip
  const int rbase = rg * 16;

  // 24 horizontal 9-tap sums: csum rows rbase..rbase+23, cols cc..cc+8
  float h[24];
#pragma unroll
  for (int k = 0; k < 24; ++k) {
    const float* row = &csum[rbase + k][cc];
    float s = row[0];
#pragma unroll
    for (int d = 1; d < 9; ++d) s += row[d];
    h[k] = s;
  }

  // Vertical running 9-window + fuse + store
  const float inv81 = 1.0f / 81.0f;
  float s = 0.f;
#pragma unroll
  for (int k = 0; k < 9; ++k) s += h[k];

#pragma unroll
  for (int it = 0; it < 16; ++it) {
    if (it > 0) s += h[it + 8] - h[it - 1];
    int gy = y0 + rbase + it;
    long pix = (long)gy * W + (x0 + cc);
    float pv = pb[pix];
    float m = s * inv81;
    float om = 1.0f - pv;
    float v0 = xb[pix];
    float v1 = xb[HW + pix];
    float v2 = xb[2 * HW + pix];
    ob[pix] = pv * v0 + om * m;
    ob[HW + pix] = pv * v1 + om * m;
    ob[2 * HW + pix] = pv * v2 + om * m;
  }
}

extern "C" void kernel_launch(void* const* d_in, const int* in_sizes, int n_in,
                              void* d_out, int out_size, void* d_ws, size_t ws_size,
                              hipStream_t stream) {
  const float* x = (const float*)d_in[0];
  const float* p = (const float*)d_in[1];
  float* out = (float*)d_out;

  const int H = 512, W = 512;
  const int B = in_sizes[1] / (H * W);  // p is (B,1,H,W) -> 32

  dim3 grid(W / TX, H / TY, B);  // (8, 8, 32) = 2048 blocks
  dim3 block(256);
  reflection_fusion_kernel<<<grid, block, 0, stream>>>(x, p, out, H, W);
}

// Round 5
// 213.767 us; speedup vs baseline: 1.0111x; 1.0086x over previous
//
#include <hip/hip_runtime.h>

// ReflectionFusion: out = p*x + (1-p)*boxmean9x9(sum_c x)  (zero padding)
// x: (32,3,512,512) f32, p: (32,1,512,512) f32, out: (32,3,512,512) f32.
// All 3 conv output channels identical -> channel-sum once, separable 9x9 box.
//
// R2 design: 256x16 tile so every wave touches 1KB-contiguous segments per
// stream (R0/R1 at 64-wide tiles = 256B segments stuck at 3.25 TB/s with all
// pipes idle -> DRAM burst-granularity theory). Stage 3 is float4 end-to-end
// (p load, x re-reads, stores). Single 24x272 f32 LDS buffer (26.1 KB,
// 6 blocks/CU), one barrier, h-sums + vertical running window in registers.

#define TX 256
#define TY 16
#define CROWS (TY + 8)   // 24 rows: y0-4 .. y0+19
#define CCOLS 272        // cols x0-8 .. x0+263 (16B-aligned start, covers +-4 halo)

__global__ __launch_bounds__(256) void reflection_fusion_kernel(
    const float* __restrict__ x, const float* __restrict__ p,
    float* __restrict__ out, int H, int W) {
  __shared__ __align__(16) float csum[CROWS][CCOLS];  // 26112 B

  const int tid = threadIdx.x;
  const int b = blockIdx.z;
  const int x0 = blockIdx.x * TX;
  const int y0 = blockIdx.y * TY;
  const long HW = (long)H * W;
  const float* xb = x + (long)b * 3 * HW;
  const float* pb = p + (long)b * HW;
  float* ob = out + (long)b * 3 * HW;

  // ---- Stage 1: halo load (float4, 16B-aligned) + channel-sum into LDS ----
  // 24 rows x 68 float4-chunks = 1632 chunks.
  for (int i = tid; i < CROWS * 68; i += 256) {
    int r = (unsigned)i / 68u;
    int k = i - r * 68;
    int gy = y0 + r - 4;
    int gx = x0 + 4 * k - 8;  // 32B-aligned base; chunks fully in- or out-of-range
    float4 s = make_float4(0.f, 0.f, 0.f, 0.f);
    if ((unsigned)gy < (unsigned)H && gx >= 0 && gx + 4 <= W) {
      const float* base = xb + (long)gy * W + gx;
      float4 a = *(const float4*)(base);
      float4 c1 = *(const float4*)(base + HW);
      float4 c2 = *(const float4*)(base + 2 * HW);
      s.x = a.x + c1.x + c2.x;
      s.y = a.y + c1.y + c2.y;
      s.z = a.z + c1.z + c2.z;
      s.w = a.w + c1.w + c2.w;
    }
    *(float4*)&csum[r][4 * k] = s;
  }
  __syncthreads();

  // ---- Stage 2: horizontal 9-sums into registers ----
  // Thread -> out cols 4j..4j+3 (j=tid&63), out rows r0..r0+3 (r0=(tid>>6)*4).
  // Wave = one 4-row x 256-col slab -> all global ops 1KB contiguous.
  const int j = tid & 63;
  const int r0 = (tid >> 6) << 2;

  float h[12][4];
#pragma unroll
  for (int i = 0; i < 12; ++i) {
    // csum row r0+i covers out-row window; cols needed: 4j-4..4j+7 -> lc 4j+4..4j+15
    const float* row = &csum[r0 + i][4 * j + 4];
    float4 a = *(const float4*)(row);
    float4 bq = *(const float4*)(row + 4);
    float4 c = *(const float4*)(row + 8);
    float s9 = ((a.x + a.y) + (a.z + a.w)) + ((bq.x + bq.y) + (bq.z + bq.w)) + c.x;
    h[i][0] = s9;
    s9 += c.y - a.x; h[i][1] = s9;
    s9 += c.z - a.y; h[i][2] = s9;
    s9 += c.w - a.z; h[i][3] = s9;
  }

  // ---- Stage 3: vertical running 9-window + fuse + store (all float4) ----
  const float inv81 = 1.0f / 81.0f;
  float vs0 = 0.f, vs1 = 0.f, vs2 = 0.f, vs3 = 0.f;
#pragma unroll
  for (int i = 0; i < 9; ++i) {
    vs0 += h[i][0]; vs1 += h[i][1]; vs2 += h[i][2]; vs3 += h[i][3];
  }

#pragma unroll
  for (int it = 0; it < 4; ++it) {
    if (it > 0) {
      vs0 += h[it + 8][0] - h[it - 1][0];
      vs1 += h[it + 8][1] - h[it - 1][1];
      vs2 += h[it + 8][2] - h[it - 1][2];
      vs3 += h[it + 8][3] - h[it - 1][3];
    }
    int gy = y0 + r0 + it;
    long pix = (long)gy * W + (x0 + 4 * j);
    float4 pv = *(const float4*)(pb + pix);
    float4 m = make_float4(vs0 * inv81, vs1 * inv81, vs2 * inv81, vs3 * inv81);
    float4 om = make_float4(1.f - pv.x, 1.f - pv.y, 1.f - pv.z, 1.f - pv.w);
    float4 t0 = make_float4(om.x * m.x, om.y * m.y, om.z * m.z, om.w * m.w);
#pragma unroll
    for (int c = 0; c < 3; ++c) {
      const float* xs = xb + c * HW + pix;
      float4 xv = *(const float4*)(xs);
      float4 o;
      o.x = pv.x * xv.x + t0.x;
      o.y = pv.y * xv.y + t0.y;
      o.z = pv.z * xv.z + t0.z;
      o.w = pv.w * xv.w + t0.w;
      *(float4*)(ob + c * HW + pix) = o;
    }
  }
}

extern "C" void kernel_launch(void* const* d_in, const int* in_sizes, int n_in,
                              void* d_out, int out_size, void* d_ws, size_t ws_size,
                              hipStream_t stream) {
  const float* x = (const float*)d_in[0];
  const float* p = (const float*)d_in[1];
  float* out = (float*)d_out;

  const int H = 512, W = 512;
  const int B = in_sizes[1] / (H * W);  // p is (B,1,H,W) -> 32

  dim3 grid(W / TX, H / TY, B);  // (2, 32, 32) = 2048 blocks
  dim3 block(256);
  reflection_fusion_kernel<<<grid, block, 0, stream>>>(x, p, out, H, W);
}